// Round 9
// baseline (155.127 us; speedup 1.0000x reference)
//
#include <hip/hip_runtime.h>
#include <hip/hip_bf16.h>
#include <hip/hip_cooperative_groups.h>
#include <string.h>

namespace cg = cooperative_groups;

#define NUM_CLASS 4096
#define HIDDEN    512
#define NGROUPS   64
#define BATCH     64

// ws layout (int offsets):
//   [10240..18431]    inv[2][4096]     (scatter fallback only)
//   float idx 16384+: tmp[kh][h][class 4096][b 64]
#define WS_INV   10240
#define TMP_OFF_F 16384
#define TMP_H_STRIDE (4096*64)       // floats per (kh,h) slice (1 MiB)
#define TMP_S_STRIDE (2*4096*64)     // floats per kh step (2 MiB)

typedef __attribute__((ext_vector_type(8))) short short8;
typedef __attribute__((ext_vector_type(4))) float f32x4;

__device__ __forceinline__ unsigned int pack2bf(float a, float b) {
    __hip_bfloat16 ha = __float2bfloat16(a), hb = __float2bfloat16(b);
    unsigned short ua, ub;
    memcpy(&ua, &ha, 2); memcpy(&ub, &hb, 2);
    return (unsigned int)ua | ((unsigned int)ub << 16);
}

// only needed for the scatter fallback (tiny ws): builds inv permutation
__global__ __launch_bounds__(1024) void prep_inv_kernel(
    const int* __restrict__ co_idx, const int* __restrict__ cl_idx,
    int* __restrict__ ws)
{
    int tid = threadIdx.x;
    for (int v = tid; v < 2 * NUM_CLASS; v += 1024) {
        int h = v >> 12, c = v & (NUM_CLASS - 1);
        const int* idx = h ? cl_idx : co_idx;
        ws[WS_INV + h * NUM_CLASS + idx[c]] = c;
    }
}

// chunk-slot GEMM body: block = (chunk of 64 classes, h, kh). No worklist,
// no early return (fused-safe). Segment scan via ballot; one MFMA pass per
// segment; merge valid slots into ftile; dense class-indexed tmp write.
template<int KS, bool SCATTER>
__device__ __forceinline__ void stage1_body(
    const float* __restrict__ x,
    const float* __restrict__ co_W, const float* __restrict__ cl_W,
    const float* __restrict__ co_b, const float* __restrict__ cl_b,
    const int* __restrict__ co_gof, const int* __restrict__ cl_gof,
    int* __restrict__ ws, float* __restrict__ out)
{
    const int NCH = 8 / KS;          // k-chunks of 64 per block
    const int nblk = 128 * KS;       // 64 chunks * 2 h * KS
    const int chunk = nblk >> 3;
    int bid = blockIdx.x;
    int swz = (bid & 7) * chunk + (bid >> 3);
    int cid = swz & 63;              // class chunk id
    int hk  = swz >> 6;
    int h   = hk & 1;
    int kh  = hk >> 1;
    int c0  = cid * 64;

    const float* Wp  = h ? cl_W : co_W;
    const int*   gof = h ? cl_gof : co_gof;

    __shared__ __align__(16) unsigned short Xs[64][72];
    __shared__ __align__(16) unsigned short Wls[64][72];
    __shared__ float ftile[64][65];
    __shared__ int s_seg_lo[65];
    __shared__ int s_seg_g[64];
    __shared__ int s_nseg;

    int tid = threadIdx.x;
    int l = tid & 63, w = tid >> 6;

    // --- segment scan (wave 0) ---
    if (tid < 64) {
        int gi = gof[c0 + tid];
        int prev = (tid == 0) ? -1 : gof[c0 + tid - 1];
        bool is_start = (gi != prev);
        unsigned long long m = __ballot(is_start);
        int segidx = (int)__popcll(m & ((1ull << tid) - 1ull));
        if (is_start) { s_seg_lo[segidx] = tid; s_seg_g[segidx] = gi; }
        if (tid == 0) {
            int ns = (int)__popcll(m);
            s_nseg = ns;
            s_seg_lo[ns] = 64;
        }
    }

    int rowq[4], kvq[4];
    #pragma unroll
    for (int q = 0; q < 4; ++q) {
        int v = q * 256 + tid;
        rowq[q] = v >> 4;
        kvq[q]  = v & 15;
    }

    float4 rxA[4], rwA[4], rxB[4], rwB[4];
    f32x4 acc[4];
    #pragma unroll
    for (int i = 0; i < 4; ++i) acc[i] = (f32x4)(0.0f);

    const int kbase = kh * (HIDDEN / KS);

#define LOADC(S, RX, RW, NEEDW) do {                                                \
    int si_ = (S) / NCH, t_ = (S) % NCH;                                            \
    int k0_ = kbase + t_ * 64;                                                      \
    int xr_ = h * 64 + s_seg_g[si_];                                                \
    _Pragma("unroll")                                                               \
    for (int q = 0; q < 4; ++q) {                                                   \
        RX[q] = *(const float4*)(x + rowq[q] * 65536 + xr_ * 512 + k0_ + kvq[q]*4); \
        if (NEEDW)                                                                  \
            RW[q] = *(const float4*)(Wp + (c0 + rowq[q]) * 512 + k0_ + kvq[q] * 4); \
    } } while (0)

#define STOREC(RX, RW, NEEDW) do {                                                  \
    _Pragma("unroll")                                                               \
    for (int q = 0; q < 4; ++q) {                                                   \
        unsigned int x0 = pack2bf(RX[q].x, RX[q].y);                                \
        unsigned int x1 = pack2bf(RX[q].z, RX[q].w);                                \
        *(uint2*)&Xs[rowq[q]][kvq[q] * 4] = make_uint2(x0, x1);                     \
        if (NEEDW) {                                                                \
            unsigned int w0 = pack2bf(RW[q].x, RW[q].y);                            \
            unsigned int w1 = pack2bf(RW[q].z, RW[q].w);                            \
            *(uint2*)&Wls[rowq[q]][kvq[q] * 4] = make_uint2(w0, w1);                \
        }                                                                           \
    } } while (0)

#define COMPUTEC() do {                                                             \
    _Pragma("unroll")                                                               \
    for (int kq = 0; kq < 2; ++kq) {                                                \
        int koff = kq * 32 + (l >> 4) * 8;                                          \
        short8 bfrag = *(const short8*)&Wls[w * 16 + (l & 15)][koff];               \
        _Pragma("unroll")                                                           \
        for (int i = 0; i < 4; ++i) {                                               \
            short8 afrag = *(const short8*)&Xs[16 * i + (l & 15)][koff];            \
            acc[i] = __builtin_amdgcn_mfma_f32_16x16x32_bf16(afrag, bfrag, acc[i],  \
                                                             0, 0, 0);              \
        }                                                                           \
    } } while (0)

    __syncthreads();   // segment data ready
    int nseg = s_nseg;
    int nsteps = nseg * NCH;
    int slotw = w * 16 + (l & 15);

    LOADC(0, rxA, rwA, true);
    STOREC(rxA, rwA, true);
    __syncthreads();

    #pragma unroll 1
    for (int s = 0; s < nsteps; ++s) {
        bool nxt = (s + 1 < nsteps);
        const bool needW = (NCH > 1);   // NCH==1: W staged once at step 0
        if (nxt) {
            if (s & 1) LOADC(s + 1, rxA, rwA, needW);
            else       LOADC(s + 1, rxB, rwB, needW);
        }
        COMPUTEC();
        if ((s % NCH) == NCH - 1) {
            int si = s / NCH;
            int lo = s_seg_lo[si], hi = s_seg_lo[si + 1];
            if (slotw >= lo && slotw < hi) {
                #pragma unroll
                for (int i = 0; i < 4; ++i)
                    #pragma unroll
                    for (int r = 0; r < 4; ++r)
                        ftile[slotw][16 * i + (l >> 4) * 4 + r] = acc[i][r];
            }
            #pragma unroll
            for (int i = 0; i < 4; ++i) acc[i] = (f32x4)(0.0f);
        }
        __syncthreads();
        if (nxt) {
            if (s & 1) STOREC(rxA, rwA, needW);
            else       STOREC(rxB, rwB, needW);
            __syncthreads();
        }
    }

    if (!SCATTER) {
        float* tmph = (float*)ws + TMP_OFF_F + (size_t)(kh * 2 + h) * TMP_H_STRIDE;
        #pragma unroll
        for (int p = 0; p < 4; ++p) {
            int f = p * 256 + tid;
            int slot = f >> 4, b4 = (f & 15) * 4;
            *(float4*)&tmph[(size_t)(c0 + slot) * 64 + b4] =
                *(const float4*)&ftile[slot][b4];
        }
    } else {
        const float* bias = h ? cl_b : co_b;
        const int*   inv  = ws + WS_INV + h * NUM_CLASS;
        float* outh = out + (size_t)h * BATCH * NUM_CLASS;
        #pragma unroll
        for (int p = 0; p < 4; ++p) {
            int f = p * 256 + tid;
            int slot = f >> 4, b4 = (f & 15) * 4;
            int c = c0 + slot;
            int oc = inv[c];
            float bb = bias[c];
            #pragma unroll
            for (int e = 0; e < 4; ++e)
                outh[(b4 + e) * 4096 + oc] = ftile[slot][b4 + e] + bb;
        }
    }
#undef LOADC
#undef STOREC
#undef COMPUTEC
}

// gather-free permute body: work item pb = (h<<6)|jc -> 64 out columns x 64 b.
template<int KS>
__device__ __forceinline__ void permute_body(
    int pb, const int* __restrict__ ws,
    const float* __restrict__ co_b, const float* __restrict__ cl_b,
    const int* __restrict__ co_idx, const int* __restrict__ cl_idx,
    float* __restrict__ out)
{
    int jc = pb & 63;
    int h  = pb >> 6;
    const float* bias = h ? cl_b : co_b;
    const int*   idx  = h ? cl_idx : co_idx;
    const float* tmph = (const float*)ws + TMP_OFF_F + (size_t)h * TMP_H_STRIDE;

    __shared__ float tile[64][65];
    int tid = threadIdx.x;
    int lane = tid & 63, w = tid >> 6;

    #pragma unroll
    for (int u = 0; u < 16; ++u) {
        int jj = u * 4 + w;               // 0..63, wave-uniform
        int j  = jc * 64 + jj;
        int c  = idx[j];                  // wave-uniform scalar
        float v = bias[c];
        #pragma unroll
        for (int s = 0; s < KS; ++s)
            v += tmph[(size_t)s * TMP_S_STRIDE + (size_t)c * 64 + lane];
        tile[lane][jj] = v;               // [b][j], stride 65 -> conflict-free
    }
    __syncthreads();

    #pragma unroll
    for (int p = 0; p < 4; ++p) {
        int f = p * 256 + tid;
        int b = f >> 4, j4 = (f & 15) * 4;
        *(float4*)&out[((size_t)h * 64 + b) * 4096 + jc * 64 + j4] =
            *(const float4*)&tile[b][j4];
    }
}

template<int KS, bool SCATTER>
__global__ __launch_bounds__(256, 4) void gwl_stage1(
    const float* __restrict__ x,
    const float* __restrict__ co_W, const float* __restrict__ cl_W,
    const float* __restrict__ co_b, const float* __restrict__ cl_b,
    const int* __restrict__ co_gof, const int* __restrict__ cl_gof,
    int* __restrict__ ws, float* __restrict__ out)
{
    stage1_body<KS, SCATTER>(x, co_W, cl_W, co_b, cl_b, co_gof, cl_gof, ws, out);
}

template<int KS>
__global__ __launch_bounds__(256) void gwl_permute(
    const int* __restrict__ ws,
    const float* __restrict__ co_b, const float* __restrict__ cl_b,
    const int* __restrict__ co_idx, const int* __restrict__ cl_idx,
    float* __restrict__ out)
{
    permute_body<KS>(blockIdx.y * 64 + blockIdx.x, ws, co_b, cl_b,
                     co_idx, cl_idx, out);
}

// fused cooperative kernel: phase A GEMM -> grid sync -> phase B permute
template<int KS>
__global__ __launch_bounds__(256, 2) void gwl_fused(
    const float* __restrict__ x,
    const float* __restrict__ co_W, const float* __restrict__ cl_W,
    const float* __restrict__ co_b, const float* __restrict__ cl_b,
    const int* __restrict__ co_gof, const int* __restrict__ cl_gof,
    const int* __restrict__ co_idx, const int* __restrict__ cl_idx,
    int* __restrict__ ws, float* __restrict__ out)
{
    stage1_body<KS, false>(x, co_W, cl_W, co_b, cl_b, co_gof, cl_gof, ws, out);
    __threadfence();
    cg::this_grid().sync();
    if (blockIdx.x < 128)
        permute_body<KS>(blockIdx.x, ws, co_b, cl_b, co_idx, cl_idx, out);
}

extern "C" void kernel_launch(void* const* d_in, const int* in_sizes, int n_in,
                              void* d_out, int out_size, void* d_ws, size_t ws_size,
                              hipStream_t stream)
{
    (void)in_sizes; (void)n_in; (void)out_size;
    const float* x      = (const float*)d_in[0];
    const float* co_W   = (const float*)d_in[1];
    const float* cl_W   = (const float*)d_in[2];
    const float* co_b   = (const float*)d_in[3];
    const float* cl_b   = (const float*)d_in[4];
    const int*   co_gof = (const int*)d_in[5];
    const int*   cl_gof = (const int*)d_in[6];
    const int*   co_idx = (const int*)d_in[7];
    const int*   cl_idx = (const int*)d_in[8];
    int*   ws  = (int*)d_ws;
    float* out = (float*)d_out;

    const size_t base  = (size_t)TMP_OFF_F * 4;
    const size_t slice = (size_t)TMP_S_STRIDE * 4;   // 2 MiB per kh step

    // primary: fused cooperative kernel (KS=4, 512 blocks = 2/CU)
    if (ws_size >= base + 4 * slice) {
        void* args[] = {
            (void*)&x, (void*)&co_W, (void*)&cl_W, (void*)&co_b, (void*)&cl_b,
            (void*)&co_gof, (void*)&cl_gof, (void*)&co_idx, (void*)&cl_idx,
            (void*)&ws, (void*)&out
        };
        hipError_t e = hipLaunchCooperativeKernel(gwl_fused<4>, dim3(512),
                                                  dim3(256), args, 0, stream);
        if (e == hipSuccess) return;
        (void)hipGetLastError();   // clear error state, fall through
    }

    // fallback: proven 2-kernel path
    if (ws_size >= base + 4 * slice) {
        hipLaunchKernelGGL((gwl_stage1<4, false>), dim3(512), dim3(256), 0, stream,
                           x, co_W, cl_W, co_b, cl_b, co_gof, cl_gof, ws, out);
        hipLaunchKernelGGL((gwl_permute<4>), dim3(64, 2), dim3(256), 0, stream,
                           ws, co_b, cl_b, co_idx, cl_idx, out);
    } else if (ws_size >= base + 2 * slice) {
        hipLaunchKernelGGL((gwl_stage1<2, false>), dim3(256), dim3(256), 0, stream,
                           x, co_W, cl_W, co_b, cl_b, co_gof, cl_gof, ws, out);
        hipLaunchKernelGGL((gwl_permute<2>), dim3(64, 2), dim3(256), 0, stream,
                           ws, co_b, cl_b, co_idx, cl_idx, out);
    } else if (ws_size >= base + 1 * slice) {
        hipLaunchKernelGGL((gwl_stage1<1, false>), dim3(128), dim3(256), 0, stream,
                           x, co_W, cl_W, co_b, cl_b, co_gof, cl_gof, ws, out);
        hipLaunchKernelGGL((gwl_permute<1>), dim3(64, 2), dim3(256), 0, stream,
                           ws, co_b, cl_b, co_idx, cl_idx, out);
    } else {
        hipLaunchKernelGGL(prep_inv_kernel, dim3(1), dim3(1024), 0, stream,
                           co_idx, cl_idx, ws);
        hipLaunchKernelGGL((gwl_stage1<1, true>), dim3(128), dim3(256), 0, stream,
                           x, co_W, cl_W, co_b, cl_b, co_gof, cl_gof, ws, out);
    }
}

// Round 10
// 74.755 us; speedup vs baseline: 2.0751x; 2.0751x over previous
//
#include <hip/hip_runtime.h>
#include <hip/hip_bf16.h>
#include <string.h>

#define NUM_CLASS 4096
#define HIDDEN    512
#define NGROUPS   64
#define BATCH     64

// ws layout (int offsets):
//   [0..15]           grid-barrier counter (zeroed via hipMemsetAsync each call)
//   [10240..18431]    inv[2][4096]     (scatter fallback only)
//   float idx 16384+: tmp[kh][h][class 4096][b 64]
#define WS_INV   10240
#define TMP_OFF_F 16384
#define TMP_H_STRIDE (4096*64)       // floats per (kh,h) slice (1 MiB)
#define TMP_S_STRIDE (2*4096*64)     // floats per kh step (2 MiB)

typedef __attribute__((ext_vector_type(8))) short short8;
typedef __attribute__((ext_vector_type(4))) float f32x4;

__device__ __forceinline__ unsigned int pack2bf(float a, float b) {
    __hip_bfloat16 ha = __float2bfloat16(a), hb = __float2bfloat16(b);
    unsigned short ua, ub;
    memcpy(&ua, &ha, 2); memcpy(&ub, &hb, 2);
    return (unsigned int)ua | ((unsigned int)ub << 16);
}

// only needed for the scatter fallback (tiny ws): builds inv permutation
__global__ __launch_bounds__(1024) void prep_inv_kernel(
    const int* __restrict__ co_idx, const int* __restrict__ cl_idx,
    int* __restrict__ ws)
{
    int tid = threadIdx.x;
    for (int v = tid; v < 2 * NUM_CLASS; v += 1024) {
        int h = v >> 12, c = v & (NUM_CLASS - 1);
        const int* idx = h ? cl_idx : co_idx;
        ws[WS_INV + h * NUM_CLASS + idx[c]] = c;
    }
}

// chunk-slot GEMM body: block = (chunk of 64 classes, h, kh). No worklist,
// no early return (fused-safe). Segment scan via ballot; one MFMA pass per
// segment; merge valid slots into ftile; dense class-indexed tmp write.
template<int KS, bool SCATTER>
__device__ __forceinline__ void stage1_body(
    const float* __restrict__ x,
    const float* __restrict__ co_W, const float* __restrict__ cl_W,
    const float* __restrict__ co_b, const float* __restrict__ cl_b,
    const int* __restrict__ co_gof, const int* __restrict__ cl_gof,
    int* __restrict__ ws, float* __restrict__ out)
{
    const int NCH = 8 / KS;          // k-chunks of 64 per block
    const int nblk = 128 * KS;       // 64 chunks * 2 h * KS
    const int chunk = nblk >> 3;
    int bid = blockIdx.x;
    int swz = (bid & 7) * chunk + (bid >> 3);
    int cid = swz & 63;              // class chunk id
    int hk  = swz >> 6;
    int h   = hk & 1;
    int kh  = hk >> 1;
    int c0  = cid * 64;

    const float* Wp  = h ? cl_W : co_W;
    const int*   gof = h ? cl_gof : co_gof;

    __shared__ __align__(16) unsigned short Xs[64][72];
    __shared__ __align__(16) unsigned short Wls[64][72];
    __shared__ float ftile[64][65];
    __shared__ int s_seg_lo[65];
    __shared__ int s_seg_g[64];
    __shared__ int s_nseg;

    int tid = threadIdx.x;
    int l = tid & 63, w = tid >> 6;

    // --- segment scan (wave 0) ---
    if (tid < 64) {
        int gi = gof[c0 + tid];
        int prev = (tid == 0) ? -1 : gof[c0 + tid - 1];
        bool is_start = (gi != prev);
        unsigned long long m = __ballot(is_start);
        int segidx = (int)__popcll(m & ((1ull << tid) - 1ull));
        if (is_start) { s_seg_lo[segidx] = tid; s_seg_g[segidx] = gi; }
        if (tid == 0) {
            int ns = (int)__popcll(m);
            s_nseg = ns;
            s_seg_lo[ns] = 64;
        }
    }

    int rowq[4], kvq[4];
    #pragma unroll
    for (int q = 0; q < 4; ++q) {
        int v = q * 256 + tid;
        rowq[q] = v >> 4;
        kvq[q]  = v & 15;
    }

    float4 rxA[4], rwA[4], rxB[4], rwB[4];
    f32x4 acc[4];
    #pragma unroll
    for (int i = 0; i < 4; ++i) acc[i] = (f32x4)(0.0f);

    const int kbase = kh * (HIDDEN / KS);

#define LOADC(S, RX, RW, NEEDW) do {                                                \
    int si_ = (S) / NCH, t_ = (S) % NCH;                                            \
    int k0_ = kbase + t_ * 64;                                                      \
    int xr_ = h * 64 + s_seg_g[si_];                                                \
    _Pragma("unroll")                                                               \
    for (int q = 0; q < 4; ++q) {                                                   \
        RX[q] = *(const float4*)(x + rowq[q] * 65536 + xr_ * 512 + k0_ + kvq[q]*4); \
        if (NEEDW)                                                                  \
            RW[q] = *(const float4*)(Wp + (c0 + rowq[q]) * 512 + k0_ + kvq[q] * 4); \
    } } while (0)

#define STOREC(RX, RW, NEEDW) do {                                                  \
    _Pragma("unroll")                                                               \
    for (int q = 0; q < 4; ++q) {                                                   \
        unsigned int x0 = pack2bf(RX[q].x, RX[q].y);                                \
        unsigned int x1 = pack2bf(RX[q].z, RX[q].w);                                \
        *(uint2*)&Xs[rowq[q]][kvq[q] * 4] = make_uint2(x0, x1);                     \
        if (NEEDW) {                                                                \
            unsigned int w0 = pack2bf(RW[q].x, RW[q].y);                            \
            unsigned int w1 = pack2bf(RW[q].z, RW[q].w);                            \
            *(uint2*)&Wls[rowq[q]][kvq[q] * 4] = make_uint2(w0, w1);                \
        }                                                                           \
    } } while (0)

#define COMPUTEC() do {                                                             \
    _Pragma("unroll")                                                               \
    for (int kq = 0; kq < 2; ++kq) {                                                \
        int koff = kq * 32 + (l >> 4) * 8;                                          \
        short8 bfrag = *(const short8*)&Wls[w * 16 + (l & 15)][koff];               \
        _Pragma("unroll")                                                           \
        for (int i = 0; i < 4; ++i) {                                               \
            short8 afrag = *(const short8*)&Xs[16 * i + (l & 15)][koff];            \
            acc[i] = __builtin_amdgcn_mfma_f32_16x16x32_bf16(afrag, bfrag, acc[i],  \
                                                             0, 0, 0);              \
        }                                                                           \
    } } while (0)

    __syncthreads();   // segment data ready
    int nseg = s_nseg;
    int nsteps = nseg * NCH;
    int slotw = w * 16 + (l & 15);

    LOADC(0, rxA, rwA, true);
    STOREC(rxA, rwA, true);
    __syncthreads();

    #pragma unroll 1
    for (int s = 0; s < nsteps; ++s) {
        bool nxt = (s + 1 < nsteps);
        const bool needW = (NCH > 1);   // NCH==1: W staged once at step 0
        if (nxt) {
            if (s & 1) LOADC(s + 1, rxA, rwA, needW);
            else       LOADC(s + 1, rxB, rwB, needW);
        }
        COMPUTEC();
        if ((s % NCH) == NCH - 1) {
            int si = s / NCH;
            int lo = s_seg_lo[si], hi = s_seg_lo[si + 1];
            if (slotw >= lo && slotw < hi) {
                #pragma unroll
                for (int i = 0; i < 4; ++i)
                    #pragma unroll
                    for (int r = 0; r < 4; ++r)
                        ftile[slotw][16 * i + (l >> 4) * 4 + r] = acc[i][r];
            }
            #pragma unroll
            for (int i = 0; i < 4; ++i) acc[i] = (f32x4)(0.0f);
        }
        __syncthreads();
        if (nxt) {
            if (s & 1) STOREC(rxA, rwA, needW);
            else       STOREC(rxB, rwB, needW);
            __syncthreads();
        }
    }

    if (!SCATTER) {
        float* tmph = (float*)ws + TMP_OFF_F + (size_t)(kh * 2 + h) * TMP_H_STRIDE;
        #pragma unroll
        for (int p = 0; p < 4; ++p) {
            int f = p * 256 + tid;
            int slot = f >> 4, b4 = (f & 15) * 4;
            *(float4*)&tmph[(size_t)(c0 + slot) * 64 + b4] =
                *(const float4*)&ftile[slot][b4];
        }
    } else {
        const float* bias = h ? cl_b : co_b;
        const int*   inv  = ws + WS_INV + h * NUM_CLASS;
        float* outh = out + (size_t)h * BATCH * NUM_CLASS;
        #pragma unroll
        for (int p = 0; p < 4; ++p) {
            int f = p * 256 + tid;
            int slot = f >> 4, b4 = (f & 15) * 4;
            int c = c0 + slot;
            int oc = inv[c];
            float bb = bias[c];
            #pragma unroll
            for (int e = 0; e < 4; ++e)
                outh[(b4 + e) * 4096 + oc] = ftile[slot][b4 + e] + bb;
        }
    }
#undef LOADC
#undef STOREC
#undef COMPUTEC
}

// gather-free permute body: work item pb = (h<<6)|jc -> 64 out columns x 64 b.
template<int KS>
__device__ __forceinline__ void permute_body(
    int pb, const int* __restrict__ ws,
    const float* __restrict__ co_b, const float* __restrict__ cl_b,
    const int* __restrict__ co_idx, const int* __restrict__ cl_idx,
    float* __restrict__ out)
{
    int jc = pb & 63;
    int h  = pb >> 6;
    const float* bias = h ? cl_b : co_b;
    const int*   idx  = h ? cl_idx : co_idx;
    const float* tmph = (const float*)ws + TMP_OFF_F + (size_t)h * TMP_H_STRIDE;

    __shared__ float tile[64][65];
    int tid = threadIdx.x;
    int lane = tid & 63, w = tid >> 6;

    #pragma unroll
    for (int u = 0; u < 16; ++u) {
        int jj = u * 4 + w;               // 0..63, wave-uniform
        int j  = jc * 64 + jj;
        int c  = idx[j];                  // wave-uniform scalar
        float v = bias[c];
        #pragma unroll
        for (int s = 0; s < KS; ++s)
            v += tmph[(size_t)s * TMP_S_STRIDE + (size_t)c * 64 + lane];
        tile[lane][jj] = v;               // [b][j], stride 65 -> conflict-free
    }
    __syncthreads();

    #pragma unroll
    for (int p = 0; p < 4; ++p) {
        int f = p * 256 + tid;
        int b = f >> 4, j4 = (f & 15) * 4;
        *(float4*)&out[((size_t)h * 64 + b) * 4096 + jc * 64 + j4] =
            *(const float4*)&tile[b][j4];
    }
}

template<int KS, bool SCATTER>
__global__ __launch_bounds__(256, 4) void gwl_stage1(
    const float* __restrict__ x,
    const float* __restrict__ co_W, const float* __restrict__ cl_W,
    const float* __restrict__ co_b, const float* __restrict__ cl_b,
    const int* __restrict__ co_gof, const int* __restrict__ cl_gof,
    int* __restrict__ ws, float* __restrict__ out)
{
    stage1_body<KS, SCATTER>(x, co_W, cl_W, co_b, cl_b, co_gof, cl_gof, ws, out);
}

template<int KS>
__global__ __launch_bounds__(256) void gwl_permute(
    const int* __restrict__ ws,
    const float* __restrict__ co_b, const float* __restrict__ cl_b,
    const int* __restrict__ co_idx, const int* __restrict__ cl_idx,
    float* __restrict__ out)
{
    permute_body<KS>(blockIdx.y * 64 + blockIdx.x, ws, co_b, cl_b,
                     co_idx, cl_idx, out);
}

// fused kernel with hand-rolled grid barrier (NOT cooperative launch).
// Residency: grid = 128*KS = 512 blocks at KS=4; __launch_bounds__(256,2)
// -> 2 blocks/CU by design; LDS 52.7KB -> 3/CU capacity; VGPR<=256 -> >=2/CU.
// All 512 co-resident => arrive-and-spin barrier cannot deadlock.
template<int KS>
__global__ __launch_bounds__(256, 2) void gwl_fused2(
    const float* __restrict__ x,
    const float* __restrict__ co_W, const float* __restrict__ cl_W,
    const float* __restrict__ co_b, const float* __restrict__ cl_b,
    const int* __restrict__ co_gof, const int* __restrict__ cl_gof,
    const int* __restrict__ co_idx, const int* __restrict__ cl_idx,
    int* __restrict__ ws, float* __restrict__ out)
{
    stage1_body<KS, false>(x, co_W, cl_W, co_b, cl_b, co_gof, cl_gof, ws, out);

    // --- arrive: block's tmp stores are drained by the syncthreads (each
    // wave's vmcnt(0)); tid0 publishes with an agent-scope release RMW.
    __syncthreads();
    if (threadIdx.x == 0)
        __hip_atomic_fetch_add(ws, 1, __ATOMIC_RELEASE, __HIP_MEMORY_SCOPE_AGENT);

    if (blockIdx.x >= 128) return;   // producers-only blocks exit

    // --- wait: spin on the counter with sleep backoff (tid0 only)
    if (threadIdx.x == 0) {
        while (__hip_atomic_load(ws, __ATOMIC_ACQUIRE,
                                 __HIP_MEMORY_SCOPE_AGENT) < 128 * KS)
            __builtin_amdgcn_s_sleep(8);
    }
    __syncthreads();
    // per-thread acquire load -> L1/L2 invalidate so tmp reads are fresh
    int v = __hip_atomic_load(ws, __ATOMIC_ACQUIRE, __HIP_MEMORY_SCOPE_AGENT);
    asm volatile("" :: "v"(v));

    permute_body<KS>(blockIdx.x, ws, co_b, cl_b, co_idx, cl_idx, out);
}

extern "C" void kernel_launch(void* const* d_in, const int* in_sizes, int n_in,
                              void* d_out, int out_size, void* d_ws, size_t ws_size,
                              hipStream_t stream)
{
    (void)in_sizes; (void)n_in; (void)out_size;
    const float* x      = (const float*)d_in[0];
    const float* co_W   = (const float*)d_in[1];
    const float* cl_W   = (const float*)d_in[2];
    const float* co_b   = (const float*)d_in[3];
    const float* cl_b   = (const float*)d_in[4];
    const int*   co_gof = (const int*)d_in[5];
    const int*   cl_gof = (const int*)d_in[6];
    const int*   co_idx = (const int*)d_in[7];
    const int*   cl_idx = (const int*)d_in[8];
    int*   ws  = (int*)d_ws;
    float* out = (float*)d_out;

    const size_t base  = (size_t)TMP_OFF_F * 4;
    const size_t slice = (size_t)TMP_S_STRIDE * 4;   // 2 MiB per kh step

    if (ws_size >= base + 4 * slice) {
        // zero the barrier counter (deterministic per call; capture-safe)
        hipMemsetAsync(ws, 0, 64, stream);
        hipLaunchKernelGGL((gwl_fused2<4>), dim3(512), dim3(256), 0, stream,
                           x, co_W, cl_W, co_b, cl_b, co_gof, cl_gof,
                           co_idx, cl_idx, ws, out);
    } else if (ws_size >= base + 2 * slice) {
        hipLaunchKernelGGL((gwl_stage1<2, false>), dim3(256), dim3(256), 0, stream,
                           x, co_W, cl_W, co_b, cl_b, co_gof, cl_gof, ws, out);
        hipLaunchKernelGGL((gwl_permute<2>), dim3(64, 2), dim3(256), 0, stream,
                           ws, co_b, cl_b, co_idx, cl_idx, out);
    } else if (ws_size >= base + 1 * slice) {
        hipLaunchKernelGGL((gwl_stage1<1, false>), dim3(128), dim3(256), 0, stream,
                           x, co_W, cl_W, co_b, cl_b, co_gof, cl_gof, ws, out);
        hipLaunchKernelGGL((gwl_permute<1>), dim3(64, 2), dim3(256), 0, stream,
                           ws, co_b, cl_b, co_idx, cl_idx, out);
    } else {
        hipLaunchKernelGGL(prep_inv_kernel, dim3(1), dim3(1024), 0, stream,
                           co_idx, cl_idx, ws);
        hipLaunchKernelGGL((gwl_stage1<1, true>), dim3(128), dim3(256), 0, stream,
                           x, co_W, cl_W, co_b, cl_b, co_gof, cl_gof, ws, out);
    }
}

// Round 11
// 45.820 us; speedup vs baseline: 3.3856x; 1.6315x over previous
//
#include <hip/hip_runtime.h>
#include <hip/hip_bf16.h>
#include <string.h>

#define NUM_CLASS 4096
#define HIDDEN    512
#define NGROUPS   64
#define BATCH     64

// ws layout (int offsets):
//   [10240..18431]    inv[2][4096]     (scatter fallback only)
//   float idx 16384+: tmp[kh][h][class 4096][b 64]
#define WS_INV   10240
#define TMP_OFF_F 16384
#define TMP_H_STRIDE (4096*64)       // floats per (kh,h) slice (1 MiB)
#define TMP_S_STRIDE (2*4096*64)     // floats per kh step (2 MiB)

typedef __attribute__((ext_vector_type(8))) short short8;
typedef __attribute__((ext_vector_type(4))) float f32x4;

__device__ __forceinline__ unsigned int pack2bf(float a, float b) {
    __hip_bfloat16 ha = __float2bfloat16(a), hb = __float2bfloat16(b);
    unsigned short ua, ub;
    memcpy(&ua, &ha, 2); memcpy(&ub, &hb, 2);
    return (unsigned int)ua | ((unsigned int)ub << 16);
}

__device__ __forceinline__ short8 cvt8(float4 a, float4 b) {
    union { short8 s; unsigned int u[4]; } r;
    r.u[0] = pack2bf(a.x, a.y); r.u[1] = pack2bf(a.z, a.w);
    r.u[2] = pack2bf(b.x, b.y); r.u[3] = pack2bf(b.z, b.w);
    return r.s;
}

// scatter-fallback prep: inv permutation
__global__ __launch_bounds__(1024) void prep_inv_kernel(
    const int* __restrict__ co_idx, const int* __restrict__ cl_idx,
    int* __restrict__ ws)
{
    int tid = threadIdx.x;
    for (int v = tid; v < 2 * NUM_CLASS; v += 1024) {
        int h = v >> 12, c = v & (NUM_CLASS - 1);
        const int* idx = h ? cl_idx : co_idx;
        ws[WS_INV + h * NUM_CLASS + idx[c]] = c;
    }
}

// ---------------- primary: direct-from-global MFMA GEMM, no LDS staging ----
// block = (class chunk of 64, h, kh). Both MFMA fragments (A from x, B from W)
// are 8 K-consecutive elements of a row -> load straight from global + cvt.
template<int KS>
__global__ __launch_bounds__(256, 2) void gwl_gemm_direct(
    const float* __restrict__ x,
    const float* __restrict__ co_W, const float* __restrict__ cl_W,
    const int* __restrict__ co_gof, const int* __restrict__ cl_gof,
    float* __restrict__ tmp)
{
    const int KQ = (HIDDEN / KS) / 32;   // MFMA K-steps per block
    const int nblk = 128 * KS;
    const int chunk = nblk >> 3;
    int bid = blockIdx.x;
    int swz = (bid & 7) * chunk + (bid >> 3);   // XCD-chunked bijection
    int cid = swz & 63, hk = swz >> 6;
    int h = hk & 1, kh = hk >> 1;
    int c0 = cid * 64;

    const float* Wp  = h ? cl_W : co_W;
    const int*   gof = h ? cl_gof : co_gof;

    __shared__ int s_seg_lo[65];
    __shared__ int s_seg_g[64];
    __shared__ int s_nseg;

    int tid = threadIdx.x;
    if (tid < 64) {
        int gi = gof[c0 + tid];
        int prev = (tid == 0) ? -1 : gof[c0 + tid - 1];
        bool is_start = (gi != prev);
        unsigned long long m = __ballot(is_start);
        int segidx = (int)__popcll(m & ((1ull << tid) - 1ull));
        if (is_start) { s_seg_lo[segidx] = tid; s_seg_g[segidx] = gi; }
        if (tid == 0) {
            int ns = (int)__popcll(m);
            s_nseg = ns;
            s_seg_lo[ns] = 64;
        }
    }
    __syncthreads();

    int l = tid & 63, w = tid >> 6;
    int kbase = kh * (HIDDEN / KS);
    int kcol  = kbase + (l >> 4) * 8;    // per-lane K offset
    int crow  = c0 + w * 16 + (l & 15);  // this lane's class row
    int brow  = l & 15;                  // batch row base within 16-tile

    // B fragments: load once per block (W[class][K] row-major)
    short8 bfrag[KQ];
    #pragma unroll
    for (int kq = 0; kq < KQ; ++kq) {
        const float* wp = Wp + (size_t)crow * 512 + kcol + kq * 32;
        bfrag[kq] = cvt8(*(const float4*)wp, *(const float4*)(wp + 4));
    }

    float* tmph = tmp + (size_t)(kh * 2 + h) * TMP_H_STRIDE;
    int nseg  = s_nseg;
    int slotw = w * 16 + (l & 15);

    #pragma unroll 1
    for (int si = 0; si < nseg; ++si) {
        int xr = h * 64 + s_seg_g[si];
        const float* xp = x + (size_t)xr * 512 + kcol;
        f32x4 acc[4];
        #pragma unroll
        for (int i = 0; i < 4; ++i) acc[i] = (f32x4)(0.0f);

        #pragma unroll
        for (int kq = 0; kq < KQ; ++kq) {
            #pragma unroll
            for (int i = 0; i < 4; ++i) {
                const float* ap = xp + (size_t)(16 * i + brow) * 65536 + kq * 32;
                short8 af = cvt8(*(const float4*)ap, *(const float4*)(ap + 4));
                acc[i] = __builtin_amdgcn_mfma_f32_16x16x32_bf16(
                             af, bfrag[kq], acc[i], 0, 0, 0);
            }
        }

        int lo = s_seg_lo[si], hi = s_seg_lo[si + 1];
        if (slotw >= lo && slotw < hi) {
            float* tr = tmph + (size_t)crow * 64 + (l >> 4) * 4;
            #pragma unroll
            for (int i = 0; i < 4; ++i)
                *(f32x4*)(tr + 16 * i) = acc[i];
        }
    }
}

// gather-free permute: block = 32 output columns x 64 batch (grid 128 x 2).
// wave-uniform idx/bias/tmp-row reads (256B runs); LDS transpose; coalesced out.
template<int KS>
__global__ __launch_bounds__(256) void gwl_permute32(
    const float* __restrict__ tmp,
    const float* __restrict__ co_b, const float* __restrict__ cl_b,
    const int* __restrict__ co_idx, const int* __restrict__ cl_idx,
    float* __restrict__ out)
{
    int jc = blockIdx.x;   // 0..127 : 32-column chunk
    int h  = blockIdx.y;   // 0..1
    const float* bias = h ? cl_b : co_b;
    const int*   idx  = h ? cl_idx : co_idx;
    const float* tmph = tmp + (size_t)h * TMP_H_STRIDE;

    __shared__ float tile[64][33];
    int tid = threadIdx.x;
    int lane = tid & 63, w = tid >> 6;

    #pragma unroll
    for (int u = 0; u < 8; ++u) {
        int jj = u * 4 + w;               // 0..31, wave-uniform
        int j  = jc * 32 + jj;
        int c  = idx[j];                  // wave-uniform scalar
        float v = bias[c];
        #pragma unroll
        for (int s = 0; s < KS; ++s)
            v += tmph[(size_t)s * TMP_S_STRIDE + (size_t)c * 64 + lane];
        tile[lane][jj] = v;               // [b][j], stride 33 -> conflict-free
    }
    __syncthreads();

    #pragma unroll
    for (int p = 0; p < 2; ++p) {
        int f = p * 256 + tid;
        int b = f >> 3, j4 = (f & 7) * 4;
        *(float4*)&out[((size_t)h * 64 + b) * 4096 + jc * 32 + j4] =
            *(const float4*)&tile[b][j4];
    }
}

// ---------------- scatter fallback (tiny ws): R8's proven LDS-staged kernel -
__global__ __launch_bounds__(256, 4) void gwl_stage1_scatter(
    const float* __restrict__ x,
    const float* __restrict__ co_W, const float* __restrict__ cl_W,
    const float* __restrict__ co_b, const float* __restrict__ cl_b,
    const int* __restrict__ co_gof, const int* __restrict__ cl_gof,
    int* __restrict__ ws, float* __restrict__ out)
{
    const int KS = 1, NCH = 8;
    const int nblk = 128;
    const int chunk = nblk >> 3;
    int bid = blockIdx.x;
    int swz = (bid & 7) * chunk + (bid >> 3);
    int cid = swz & 63;
    int h   = swz >> 6;
    int c0  = cid * 64;

    const float* Wp  = h ? cl_W : co_W;
    const int*   gof = h ? cl_gof : co_gof;

    __shared__ __align__(16) unsigned short Xs[64][72];
    __shared__ __align__(16) unsigned short Wls[64][72];
    __shared__ float ftile[64][65];
    __shared__ int s_seg_lo[65];
    __shared__ int s_seg_g[64];
    __shared__ int s_nseg;

    int tid = threadIdx.x;
    int l = tid & 63, w = tid >> 6;

    if (tid < 64) {
        int gi = gof[c0 + tid];
        int prev = (tid == 0) ? -1 : gof[c0 + tid - 1];
        bool is_start = (gi != prev);
        unsigned long long m = __ballot(is_start);
        int segidx = (int)__popcll(m & ((1ull << tid) - 1ull));
        if (is_start) { s_seg_lo[segidx] = tid; s_seg_g[segidx] = gi; }
        if (tid == 0) {
            int ns = (int)__popcll(m);
            s_nseg = ns;
            s_seg_lo[ns] = 64;
        }
    }

    int rowq[4], kvq[4];
    #pragma unroll
    for (int q = 0; q < 4; ++q) {
        int v = q * 256 + tid;
        rowq[q] = v >> 4;
        kvq[q]  = v & 15;
    }

    float4 rxA[4], rwA[4], rxB[4], rwB[4];
    f32x4 acc[4];
    #pragma unroll
    for (int i = 0; i < 4; ++i) acc[i] = (f32x4)(0.0f);

#define LOADC(S, RX, RW, NEEDW) do {                                                \
    int si_ = (S) / NCH, t_ = (S) % NCH;                                            \
    int k0_ = t_ * 64;                                                              \
    int xr_ = h * 64 + s_seg_g[si_];                                                \
    _Pragma("unroll")                                                               \
    for (int q = 0; q < 4; ++q) {                                                   \
        RX[q] = *(const float4*)(x + rowq[q] * 65536 + xr_ * 512 + k0_ + kvq[q]*4); \
        if (NEEDW)                                                                  \
            RW[q] = *(const float4*)(Wp + (c0 + rowq[q]) * 512 + k0_ + kvq[q] * 4); \
    } } while (0)

#define STOREC(RX, RW, NEEDW) do {                                                  \
    _Pragma("unroll")                                                               \
    for (int q = 0; q < 4; ++q) {                                                   \
        unsigned int x0 = pack2bf(RX[q].x, RX[q].y);                                \
        unsigned int x1 = pack2bf(RX[q].z, RX[q].w);                                \
        *(uint2*)&Xs[rowq[q]][kvq[q] * 4] = make_uint2(x0, x1);                     \
        if (NEEDW) {                                                                \
            unsigned int w0 = pack2bf(RW[q].x, RW[q].y);                            \
            unsigned int w1 = pack2bf(RW[q].z, RW[q].w);                            \
            *(uint2*)&Wls[rowq[q]][kvq[q] * 4] = make_uint2(w0, w1);                \
        }                                                                           \
    } } while (0)

#define COMPUTEC() do {                                                             \
    _Pragma("unroll")                                                               \
    for (int kq = 0; kq < 2; ++kq) {                                                \
        int koff = kq * 32 + (l >> 4) * 8;                                          \
        short8 bfrag = *(const short8*)&Wls[w * 16 + (l & 15)][koff];               \
        _Pragma("unroll")                                                           \
        for (int i = 0; i < 4; ++i) {                                               \
            short8 afrag = *(const short8*)&Xs[16 * i + (l & 15)][koff];            \
            acc[i] = __builtin_amdgcn_mfma_f32_16x16x32_bf16(afrag, bfrag, acc[i],  \
                                                             0, 0, 0);              \
        }                                                                           \
    } } while (0)

    __syncthreads();
    int nseg = s_nseg;
    int nsteps = nseg * NCH;
    int slotw = w * 16 + (l & 15);

    LOADC(0, rxA, rwA, true);
    STOREC(rxA, rwA, true);
    __syncthreads();

    #pragma unroll 1
    for (int s = 0; s < nsteps; ++s) {
        bool nxt = (s + 1 < nsteps);
        if (nxt) {
            if (s & 1) LOADC(s + 1, rxA, rwA, true);
            else       LOADC(s + 1, rxB, rwB, true);
        }
        COMPUTEC();
        if ((s % NCH) == NCH - 1) {
            int si = s / NCH;
            int lo = s_seg_lo[si], hi = s_seg_lo[si + 1];
            if (slotw >= lo && slotw < hi) {
                #pragma unroll
                for (int i = 0; i < 4; ++i)
                    #pragma unroll
                    for (int r = 0; r < 4; ++r)
                        ftile[slotw][16 * i + (l >> 4) * 4 + r] = acc[i][r];
            }
            #pragma unroll
            for (int i = 0; i < 4; ++i) acc[i] = (f32x4)(0.0f);
        }
        __syncthreads();
        if (nxt) {
            if (s & 1) STOREC(rxA, rwA, true);
            else       STOREC(rxB, rwB, true);
            __syncthreads();
        }
    }

    const float* bias = h ? cl_b : co_b;
    const int*   inv  = ws + WS_INV + h * NUM_CLASS;
    float* outh = out + (size_t)h * BATCH * NUM_CLASS;
    #pragma unroll
    for (int p = 0; p < 4; ++p) {
        int f = p * 256 + tid;
        int slot = f >> 4, b4 = (f & 15) * 4;
        int c = c0 + slot;
        int oc = inv[c];
        float bb = bias[c];
        #pragma unroll
        for (int e = 0; e < 4; ++e)
            outh[(b4 + e) * 4096 + oc] = ftile[slot][b4 + e] + bb;
    }
#undef LOADC
#undef STOREC
#undef COMPUTEC
}

extern "C" void kernel_launch(void* const* d_in, const int* in_sizes, int n_in,
                              void* d_out, int out_size, void* d_ws, size_t ws_size,
                              hipStream_t stream)
{
    (void)in_sizes; (void)n_in; (void)out_size;
    const float* x      = (const float*)d_in[0];
    const float* co_W   = (const float*)d_in[1];
    const float* cl_W   = (const float*)d_in[2];
    const float* co_b   = (const float*)d_in[3];
    const float* cl_b   = (const float*)d_in[4];
    const int*   co_gof = (const int*)d_in[5];
    const int*   cl_gof = (const int*)d_in[6];
    const int*   co_idx = (const int*)d_in[7];
    const int*   cl_idx = (const int*)d_in[8];
    int*   ws  = (int*)d_ws;
    float* tmp = (float*)d_ws + TMP_OFF_F;
    float* out = (float*)d_out;

    const size_t base  = (size_t)TMP_OFF_F * 4;
    const size_t slice = (size_t)TMP_S_STRIDE * 4;   // 2 MiB per kh step

    if (ws_size >= base + 4 * slice) {
        hipLaunchKernelGGL((gwl_gemm_direct<4>), dim3(512), dim3(256), 0, stream,
                           x, co_W, cl_W, co_gof, cl_gof, tmp);
        hipLaunchKernelGGL((gwl_permute32<4>), dim3(128, 2), dim3(256), 0, stream,
                           tmp, co_b, cl_b, co_idx, cl_idx, out);
    } else if (ws_size >= base + 2 * slice) {
        hipLaunchKernelGGL((gwl_gemm_direct<2>), dim3(256), dim3(256), 0, stream,
                           x, co_W, cl_W, co_gof, cl_gof, tmp);
        hipLaunchKernelGGL((gwl_permute32<2>), dim3(128, 2), dim3(256), 0, stream,
                           tmp, co_b, cl_b, co_idx, cl_idx, out);
    } else if (ws_size >= base + 1 * slice) {
        hipLaunchKernelGGL((gwl_gemm_direct<1>), dim3(128), dim3(256), 0, stream,
                           x, co_W, cl_W, co_gof, cl_gof, tmp);
        hipLaunchKernelGGL((gwl_permute32<1>), dim3(128, 2), dim3(256), 0, stream,
                           tmp, co_b, cl_b, co_idx, cl_idx, out);
    } else {
        hipLaunchKernelGGL(prep_inv_kernel, dim3(1), dim3(1024), 0, stream,
                           co_idx, cl_idx, ws);
        hipLaunchKernelGGL(gwl_stage1_scatter, dim3(128), dim3(256), 0, stream,
                           x, co_W, cl_W, co_b, cl_b, co_gof, cl_gof, ws, out);
    }
}

// Round 12
// 26.956 us; speedup vs baseline: 5.7549x; 1.6998x over previous
//
#include <hip/hip_runtime.h>
#include <hip/hip_bf16.h>
#include <string.h>

#define NUM_CLASS 4096
#define HIDDEN    512
#define NGROUPS   64
#define BATCH     64

// ws layout (int offsets):
//   [10240..18431]    inv[2][4096]     (scatter fallback only)
//   float idx 16384+: tmp[kh][h][class 4096][b 64]
#define WS_INV   10240
#define TMP_OFF_F 16384
#define TMP_H_STRIDE (4096*64)       // floats per (kh,h) slice (1 MiB)
#define TMP_S_STRIDE (2*4096*64)     // floats per kh step (2 MiB)

typedef __attribute__((ext_vector_type(8))) short short8;
typedef __attribute__((ext_vector_type(4))) float f32x4;

__device__ __forceinline__ unsigned int pack2bf(float a, float b) {
    __hip_bfloat16 ha = __float2bfloat16(a), hb = __float2bfloat16(b);
    unsigned short ua, ub;
    memcpy(&ua, &ha, 2); memcpy(&ub, &hb, 2);
    return (unsigned int)ua | ((unsigned int)ub << 16);
}

__device__ __forceinline__ short8 cvt8(float4 a, float4 b) {
    union { short8 s; unsigned int u[4]; } r;
    r.u[0] = pack2bf(a.x, a.y); r.u[1] = pack2bf(a.z, a.w);
    r.u[2] = pack2bf(b.x, b.y); r.u[3] = pack2bf(b.z, b.w);
    return r.s;
}

// scatter-fallback prep: inv permutation
__global__ __launch_bounds__(1024) void prep_inv_kernel(
    const int* __restrict__ co_idx, const int* __restrict__ cl_idx,
    int* __restrict__ ws)
{
    int tid = threadIdx.x;
    for (int v = tid; v < 2 * NUM_CLASS; v += 1024) {
        int h = v >> 12, c = v & (NUM_CLASS - 1);
        const int* idx = h ? cl_idx : co_idx;
        ws[WS_INV + h * NUM_CLASS + idx[c]] = c;
    }
}

// ---------------- primary: direct-from-global MFMA GEMM ---------------------
// block = (class chunk 64, h, kh, bs). No LDS, no syncthreads. Each wave owns
// 16 classes x 32 batches; iterates only the distinct groups among its own 16
// slots (ballot/shfl loop, avg ~1.25 passes). Per pass: 8 independent float4
// loads batched (ILP), cvt->bf16, 4 MFMAs, predicated f32x4 stores to tmp.
template<int KS>
__global__ __launch_bounds__(256, (KS == 1) ? 2 : 4) void gwl_gemm_direct(
    const float* __restrict__ x,
    const float* __restrict__ co_W, const float* __restrict__ cl_W,
    const int* __restrict__ co_gof, const int* __restrict__ cl_gof,
    float* __restrict__ tmp)
{
    const int KQ = 16 / KS;              // MFMA K-steps per block (KQ*32 K)
    const int nblk = 256 * KS;           // 64 chunks * 2 h * KS kh * 2 bs
    const int chunk = nblk >> 3;
    int bid = blockIdx.x;
    int swz = (bid & 7) * chunk + (bid >> 3);   // XCD-chunked bijection
    int cid = swz & 63;
    int r1  = swz >> 6;
    int h   = r1 & 1;
    int r2  = r1 >> 1;
    int kh  = r2 & (KS - 1);
    int bs  = r2 >> ((KS == 1) ? 0 : (KS == 2) ? 1 : 2);
    int c0  = cid * 64;

    const float* Wp  = h ? cl_W : co_W;
    const int*   gof = h ? cl_gof : co_gof;

    int tid = threadIdx.x;
    int l = tid & 63, w = tid >> 6;
    int kcol  = kh * (HIDDEN / KS) + (l >> 4) * 8;  // per-lane K offset
    int crow  = c0 + w * 16 + (l & 15);             // this lane's class row
    int bbase = bs * 32 + (l & 15);                 // batch row (i adds 16)

    // B fragments: one W row per lane, loaded once (KQ*2 independent loads)
    short8 bfrag[KQ];
    #pragma unroll
    for (int kq = 0; kq < KQ; ++kq) {
        const float* wp = Wp + (size_t)crow * 512 + kcol + kq * 32;
        bfrag[kq] = cvt8(*(const float4*)wp, *(const float4*)(wp + 4));
    }

    int gl = gof[crow];                  // group of this lane's class
    float* tmph = tmp + (size_t)(kh * 2 + h) * TMP_H_STRIDE;

    unsigned int pend = 0xFFFFu;         // slot bits 0..15 (lanes 0-15 pattern)
    while (pend) {
        int slot0 = (int)__builtin_ctz(pend);
        int g = __shfl(gl, slot0);       // wave-uniform group for this pass
        unsigned long long eq = __ballot(gl == g);
        pend &= ~(unsigned int)(eq & 0xFFFFu);

        int xr = h * 64 + g;
        const float* xp = x + (size_t)xr * 512 + kcol;

        f32x4 acc0 = (f32x4)(0.0f), acc1 = (f32x4)(0.0f);
        #pragma unroll
        for (int kp = 0; kp < KQ; kp += 2) {
            // batch 8 independent float4 loads (2 kq x 2 i x 2 halves)
            float4 f[8];
            #pragma unroll
            for (int kq2 = 0; kq2 < 2; ++kq2)
                #pragma unroll
                for (int i = 0; i < 2; ++i) {
                    const float* ap = xp + (size_t)(bbase + i * 16) * 65536
                                    + (kp + kq2) * 32;
                    f[(kq2 * 2 + i) * 2]     = *(const float4*)ap;
                    f[(kq2 * 2 + i) * 2 + 1] = *(const float4*)(ap + 4);
                }
            #pragma unroll
            for (int kq2 = 0; kq2 < 2; ++kq2) {
                short8 a0 = cvt8(f[(kq2 * 2 + 0) * 2], f[(kq2 * 2 + 0) * 2 + 1]);
                short8 a1 = cvt8(f[(kq2 * 2 + 1) * 2], f[(kq2 * 2 + 1) * 2 + 1]);
                acc0 = __builtin_amdgcn_mfma_f32_16x16x32_bf16(
                           a0, bfrag[kp + kq2], acc0, 0, 0, 0);
                acc1 = __builtin_amdgcn_mfma_f32_16x16x32_bf16(
                           a1, bfrag[kp + kq2], acc1, 0, 0, 0);
            }
        }

        if (gl == g) {
            // lane stores batches bs*32 + i*16 + (l>>4)*4 .. +3 of class crow
            float* tr = tmph + (size_t)crow * 64 + bs * 32 + (l >> 4) * 4;
            *(f32x4*)(tr)      = acc0;
            *(f32x4*)(tr + 16) = acc1;
        }
    }
}

// gather-free permute: block = 32 output columns x 64 batch (grid 128 x 2).
// wave-uniform idx/bias/tmp-row reads (256B runs); LDS transpose; coalesced out.
template<int KS>
__global__ __launch_bounds__(256) void gwl_permute32(
    const float* __restrict__ tmp,
    const float* __restrict__ co_b, const float* __restrict__ cl_b,
    const int* __restrict__ co_idx, const int* __restrict__ cl_idx,
    float* __restrict__ out)
{
    int jc = blockIdx.x;   // 0..127 : 32-column chunk
    int h  = blockIdx.y;   // 0..1
    const float* bias = h ? cl_b : co_b;
    const int*   idx  = h ? cl_idx : co_idx;
    const float* tmph = tmp + (size_t)h * TMP_H_STRIDE;

    __shared__ float tile[64][33];
    int tid = threadIdx.x;
    int lane = tid & 63, w = tid >> 6;

    #pragma unroll
    for (int u = 0; u < 8; ++u) {
        int jj = u * 4 + w;               // 0..31, wave-uniform
        int j  = jc * 32 + jj;
        int c  = idx[j];                  // wave-uniform scalar
        float v = bias[c];
        #pragma unroll
        for (int s = 0; s < KS; ++s)
            v += tmph[(size_t)s * TMP_S_STRIDE + (size_t)c * 64 + lane];
        tile[lane][jj] = v;               // [b][j], stride 33 -> conflict-free
    }
    __syncthreads();

    #pragma unroll
    for (int p = 0; p < 2; ++p) {
        int f = p * 256 + tid;
        int b = f >> 3, j4 = (f & 7) * 4;
        *(float4*)&out[((size_t)h * 64 + b) * 4096 + jc * 32 + j4] =
            *(const float4*)&tile[b][j4];
    }
}

// ---------------- scatter fallback (tiny ws): R8's proven LDS-staged kernel -
__global__ __launch_bounds__(256, 4) void gwl_stage1_scatter(
    const float* __restrict__ x,
    const float* __restrict__ co_W, const float* __restrict__ cl_W,
    const float* __restrict__ co_b, const float* __restrict__ cl_b,
    const int* __restrict__ co_gof, const int* __restrict__ cl_gof,
    int* __restrict__ ws, float* __restrict__ out)
{
    const int NCH = 8;
    const int nblk = 128;
    const int chunk = nblk >> 3;
    int bid = blockIdx.x;
    int swz = (bid & 7) * chunk + (bid >> 3);
    int cid = swz & 63;
    int h   = swz >> 6;
    int c0  = cid * 64;

    const float* Wp  = h ? cl_W : co_W;
    const int*   gof = h ? cl_gof : co_gof;

    __shared__ __align__(16) unsigned short Xs[64][72];
    __shared__ __align__(16) unsigned short Wls[64][72];
    __shared__ float ftile[64][65];
    __shared__ int s_seg_lo[65];
    __shared__ int s_seg_g[64];
    __shared__ int s_nseg;

    int tid = threadIdx.x;
    int l = tid & 63, w = tid >> 6;

    if (tid < 64) {
        int gi = gof[c0 + tid];
        int prev = (tid == 0) ? -1 : gof[c0 + tid - 1];
        bool is_start = (gi != prev);
        unsigned long long m = __ballot(is_start);
        int segidx = (int)__popcll(m & ((1ull << tid) - 1ull));
        if (is_start) { s_seg_lo[segidx] = tid; s_seg_g[segidx] = gi; }
        if (tid == 0) {
            int ns = (int)__popcll(m);
            s_nseg = ns;
            s_seg_lo[ns] = 64;
        }
    }

    int rowq[4], kvq[4];
    #pragma unroll
    for (int q = 0; q < 4; ++q) {
        int v = q * 256 + tid;
        rowq[q] = v >> 4;
        kvq[q]  = v & 15;
    }

    float4 rxA[4], rwA[4], rxB[4], rwB[4];
    f32x4 acc[4];
    #pragma unroll
    for (int i = 0; i < 4; ++i) acc[i] = (f32x4)(0.0f);

#define LOADC(S, RX, RW) do {                                                       \
    int si_ = (S) / NCH, t_ = (S) % NCH;                                            \
    int k0_ = t_ * 64;                                                              \
    int xr_ = h * 64 + s_seg_g[si_];                                                \
    _Pragma("unroll")                                                               \
    for (int q = 0; q < 4; ++q) {                                                   \
        RX[q] = *(const float4*)(x + rowq[q] * 65536 + xr_ * 512 + k0_ + kvq[q]*4); \
        RW[q] = *(const float4*)(Wp + (c0 + rowq[q]) * 512 + k0_ + kvq[q] * 4);     \
    } } while (0)

#define STOREC(RX, RW) do {                                                         \
    _Pragma("unroll")                                                               \
    for (int q = 0; q < 4; ++q) {                                                   \
        unsigned int x0 = pack2bf(RX[q].x, RX[q].y);                                \
        unsigned int x1 = pack2bf(RX[q].z, RX[q].w);                                \
        *(uint2*)&Xs[rowq[q]][kvq[q] * 4] = make_uint2(x0, x1);                     \
        unsigned int w0 = pack2bf(RW[q].x, RW[q].y);                                \
        unsigned int w1 = pack2bf(RW[q].z, RW[q].w);                                \
        *(uint2*)&Wls[rowq[q]][kvq[q] * 4] = make_uint2(w0, w1);                    \
    } } while (0)

#define COMPUTEC() do {                                                             \
    _Pragma("unroll")                                                               \
    for (int kq = 0; kq < 2; ++kq) {                                                \
        int koff = kq * 32 + (l >> 4) * 8;                                          \
        short8 bfrag = *(const short8*)&Wls[w * 16 + (l & 15)][koff];               \
        _Pragma("unroll")                                                           \
        for (int i = 0; i < 4; ++i) {                                               \
            short8 afrag = *(const short8*)&Xs[16 * i + (l & 15)][koff];            \
            acc[i] = __builtin_amdgcn_mfma_f32_16x16x32_bf16(afrag, bfrag, acc[i],  \
                                                             0, 0, 0);              \
        }                                                                           \
    } } while (0)

    __syncthreads();
    int nseg = s_nseg;
    int nsteps = nseg * NCH;
    int slotw = w * 16 + (l & 15);

    LOADC(0, rxA, rwA);
    STOREC(rxA, rwA);
    __syncthreads();

    #pragma unroll 1
    for (int s = 0; s < nsteps; ++s) {
        bool nxt = (s + 1 < nsteps);
        if (nxt) {
            if (s & 1) LOADC(s + 1, rxA, rwA);
            else       LOADC(s + 1, rxB, rwB);
        }
        COMPUTEC();
        if ((s % NCH) == NCH - 1) {
            int si = s / NCH;
            int lo = s_seg_lo[si], hi = s_seg_lo[si + 1];
            if (slotw >= lo && slotw < hi) {
                #pragma unroll
                for (int i = 0; i < 4; ++i)
                    #pragma unroll
                    for (int r = 0; r < 4; ++r)
                        ftile[slotw][16 * i + (l >> 4) * 4 + r] = acc[i][r];
            }
            #pragma unroll
            for (int i = 0; i < 4; ++i) acc[i] = (f32x4)(0.0f);
        }
        __syncthreads();
        if (nxt) {
            if (s & 1) STOREC(rxA, rwA);
            else       STOREC(rxB, rwB);
            __syncthreads();
        }
    }

    const float* bias = h ? cl_b : co_b;
    const int*   inv  = ws + WS_INV + h * NUM_CLASS;
    float* outh = out + (size_t)h * BATCH * NUM_CLASS;
    #pragma unroll
    for (int p = 0; p < 4; ++p) {
        int f = p * 256 + tid;
        int slot = f >> 4, b4 = (f & 15) * 4;
        int c = c0 + slot;
        int oc = inv[c];
        float bb = bias[c];
        #pragma unroll
        for (int e = 0; e < 4; ++e)
            outh[(b4 + e) * 4096 + oc] = ftile[slot][b4 + e] + bb;
    }
#undef LOADC
#undef STOREC
#undef COMPUTEC
}

extern "C" void kernel_launch(void* const* d_in, const int* in_sizes, int n_in,
                              void* d_out, int out_size, void* d_ws, size_t ws_size,
                              hipStream_t stream)
{
    (void)in_sizes; (void)n_in; (void)out_size;
    const float* x      = (const float*)d_in[0];
    const float* co_W   = (const float*)d_in[1];
    const float* cl_W   = (const float*)d_in[2];
    const float* co_b   = (const float*)d_in[3];
    const float* cl_b   = (const float*)d_in[4];
    const int*   co_gof = (const int*)d_in[5];
    const int*   cl_gof = (const int*)d_in[6];
    const int*   co_idx = (const int*)d_in[7];
    const int*   cl_idx = (const int*)d_in[8];
    int*   ws  = (int*)d_ws;
    float* tmp = (float*)d_ws + TMP_OFF_F;
    float* out = (float*)d_out;

    const size_t base  = (size_t)TMP_OFF_F * 4;
    const size_t slice = (size_t)TMP_S_STRIDE * 4;   // 2 MiB per kh step

    if (ws_size >= base + 4 * slice) {
        hipLaunchKernelGGL((gwl_gemm_direct<4>), dim3(1024), dim3(256), 0, stream,
                           x, co_W, cl_W, co_gof, cl_gof, tmp);
        hipLaunchKernelGGL((gwl_permute32<4>), dim3(128, 2), dim3(256), 0, stream,
                           tmp, co_b, cl_b, co_idx, cl_idx, out);
    } else if (ws_size >= base + 2 * slice) {
        hipLaunchKernelGGL((gwl_gemm_direct<2>), dim3(512), dim3(256), 0, stream,
                           x, co_W, cl_W, co_gof, cl_gof, tmp);
        hipLaunchKernelGGL((gwl_permute32<2>), dim3(128, 2), dim3(256), 0, stream,
                           tmp, co_b, cl_b, co_idx, cl_idx, out);
    } else if (ws_size >= base + 1 * slice) {
        hipLaunchKernelGGL((gwl_gemm_direct<1>), dim3(256), dim3(256), 0, stream,
                           x, co_W, cl_W, co_gof, cl_gof, tmp);
        hipLaunchKernelGGL((gwl_permute32<1>), dim3(128, 2), dim3(256), 0, stream,
                           tmp, co_b, cl_b, co_idx, cl_idx, out);
    } else {
        hipLaunchKernelGGL(prep_inv_kernel, dim3(1), dim3(1024), 0, stream,
                           co_idx, cl_idx, ws);
        hipLaunchKernelGGL(gwl_stage1_scatter, dim3(128), dim3(256), 0, stream,
                           x, co_W, cl_W, co_b, cl_b, co_gof, cl_gof, ws, out);
    }
}